// Round 7
// baseline (585.410 us; speedup 1.0000x reference)
//
#include <hip/hip_runtime.h>
#include <hip/hip_bf16.h>

#define NN 1024
#define IN_CH 128
#define EDGE_CH 32
#define OUT_CH 128
#define UDW 260          // LDS dwords per 4-e unit (256 data + 4 pad)

typedef __attribute__((ext_vector_type(8))) short bf16x8;
typedef __attribute__((ext_vector_type(4))) float f32x4;
typedef __attribute__((ext_vector_type(4))) unsigned u32x4;

// round-to-nearest-even float -> bf16 (cold paths)
static __device__ __forceinline__ short f2bf(float f) {
    union { float f; unsigned u; } v; v.f = f;
    unsigned r = v.u + 0x7FFFu + ((v.u >> 16) & 1u);
    return (short)(r >> 16);
}

// hot-path pack: two fp32 -> one dword of two bf16 (round-half-up, 4 VALU)
static __device__ __forceinline__ unsigned pack_bf2(float lo, float hi) {
    unsigned ulo = __float_as_uint(lo) + 0x8000u;
    unsigned uhi = __float_as_uint(hi) + 0x8000u;
    return (uhi & 0xFFFF0000u) | (ulo >> 16);
}

// async global->LDS DMA, 16 B/lane: lane i lands at lptr + i*16 (wave-uniform lptr).
static __device__ __forceinline__ void async_copy16(const float* gptr, float* lptr) {
    __builtin_amdgcn_global_load_lds(
        (const __attribute__((address_space(1))) void*)gptr,
        (__attribute__((address_space(3))) void*)lptr,
        16, 0, 0);
}

// ---------------------------------------------------------------------------
// Kernel A (MFMA): PF = node_mat @ node_weight (fp32), R = node_mat @ root.
// ---------------------------------------------------------------------------
__global__ void node_gemm_kernel(const float* __restrict__ node_mat,
                                 const float* __restrict__ node_weight,
                                 const float* __restrict__ root,
                                 float* __restrict__ PF,
                                 float* __restrict__ R) {
    int tid = threadIdx.x;
    int wave = tid >> 6, lane = tid & 63, quad = lane >> 4, col = lane & 15;
    int m0 = blockIdx.x * 16;

    f32x4 accP[2] = {{0.f,0.f,0.f,0.f},{0.f,0.f,0.f,0.f}};
    f32x4 accR[2] = {{0.f,0.f,0.f,0.f},{0.f,0.f,0.f,0.f}};

#pragma unroll
    for (int ks = 0; ks < 4; ++ks) {
        bf16x8 a;
#pragma unroll
        for (int j = 0; j < 8; ++j)
            a[j] = f2bf(node_mat[(m0 + col) * IN_CH + ks * 32 + quad * 8 + j]);
#pragma unroll
        for (int t = 0; t < 2; ++t) {
            int ob = (wave * 2 + t) * 16;
            bf16x8 bw, br;
#pragma unroll
            for (int j = 0; j < 8; ++j) {
                int k = ks * 32 + quad * 8 + j;
                bw[j] = f2bf(node_weight[k * OUT_CH + ob + col]);
                br[j] = f2bf(root[k * OUT_CH + ob + col]);
            }
            accP[t] = __builtin_amdgcn_mfma_f32_16x16x32_bf16(a, bw, accP[t], 0, 0, 0);
            accR[t] = __builtin_amdgcn_mfma_f32_16x16x32_bf16(a, br, accR[t], 0, 0, 0);
        }
    }
#pragma unroll
    for (int t = 0; t < 2; ++t)
#pragma unroll
        for (int r = 0; r < 4; ++r) {
            int m = m0 + quad * 4 + r;
            int o = (wave * 2 + t) * 16 + col;
            PF[(size_t)m * OUT_CH + o] = accP[t][r];
            R[(size_t)m * OUT_CH + o]  = accR[t][r];
        }
}

// ---------------------------------------------------------------------------
// Kernel B (fused, heavy): per node n computes the FULL output row.
// 4 waves; wave w = (m-half h=w&1, b-half bh=w>>1): 2x LDS-read redundancy
// (was 4x), 32 VGPR of frag state. edge_adj staged per 64-m chunk via
// global_load_lds into TRIPLE-buffered LDS; one raw s_barrier per chunk with
// our own s_waitcnt vmcnt(2) BEFORE it (no compiler vmcnt(0) drain).
// LDS unit u=e>>2 stores [p=e&3][m] at u*260 dwords -> frag reads are paired
// dword loads off 2 base regs, imm offsets <=240 dwords (ds_read2-fusable),
// 2-way banks (free). DMA writes stay 16B-contiguous.
// ---------------------------------------------------------------------------
__global__ void __launch_bounds__(256, 4)
fused_kernel(const float* __restrict__ edge_adj,
             const float* __restrict__ adj,
             const float* __restrict__ L1,
             const float* __restrict__ L2,
             const float* __restrict__ PF,
             const float* __restrict__ R,
             const float* __restrict__ bias,
             float* __restrict__ out) {
    __shared__ float ea_lds[3][8 * UDW];   // 3 x 8.3 KB
    __shared__ float adj_lds[NN];          // 4 KB
    __shared__ float gred[4][64];
    __shared__ float gs[OUT_CH];
    __shared__ float part[2][OUT_CH];

    int n = blockIdx.x;
    int tid = threadIdx.x;
    int wave = tid >> 6, lane = tid & 63, quad = lane >> 4, col = lane & 15;
    int h  = wave & 1;        // m-half within each 64-m chunk
    int bh = wave >> 1;       // b-half: b in [bh*64, bh*64+64)

    // A-frags: 4 b-tiles, b = bh*64 + bt*16 + col, e = quad*8 + j
    bf16x8 a_frag[4];
#pragma unroll
    for (int bt = 0; bt < 4; ++bt) {
        int b = bh * 64 + bt * 16 + col;
#pragma unroll
        for (int j = 0; j < 8; ++j) {
            int e = quad * 8 + j;
            a_frag[bt][j] = (b < OUT_CH - 1) ? f2bf(L1[e * (OUT_CH - 1) + b]) : (short)0;
        }
    }
    float g_acc[4][4];
#pragma unroll
    for (int bt = 0; bt < 4; ++bt)
#pragma unroll
        for (int r = 0; r < 4; ++r) g_acc[bt][r] = 0.f;

    // DMA geometry: wave w issues units u = 2w, 2w+1 per chunk.
    // lane L: e = 4u + (L>>4), m = chunk*64 + 4*(L&15); 16 B contiguous.
    const float* g0 = edge_adj + (size_t)(8 * wave + (lane >> 4)) * (size_t)(NN * NN)
                    + (size_t)n * NN + (lane & 15) * 4;
    const float* g1 = g0 + (size_t)4 * NN * NN;

    // prologue: chunk0 (2), adj row (1), chunk1 (2)
    async_copy16(g0, &ea_lds[0][(2 * wave + 0) * UDW]);
    async_copy16(g1, &ea_lds[0][(2 * wave + 1) * UDW]);
    async_copy16(adj + (size_t)n * NN + wave * 256 + lane * 4, &adj_lds[wave * 256]);
    async_copy16(g0 + 64, &ea_lds[1][(2 * wave + 0) * UDW]);
    async_copy16(g1 + 64, &ea_lds[1][(2 * wave + 1) * UDW]);

#pragma unroll
    for (int c = 0; c < 16; ++c) {
        // own chunk-c DMAs (+adj at c=0) done; chunk c+1's 2 stay in flight
        if (c < 15) __builtin_amdgcn_s_waitcnt(0xF72);   // vmcnt(2)
        else        __builtin_amdgcn_s_waitcnt(0xF70);   // vmcnt(0)
        __builtin_amdgcn_s_barrier();   // raw: no compiler vmcnt(0) drain

        // per-lane frag bases in the current buffer
        const float* b0 = &ea_lds[c % 3][(2 * quad + 0) * UDW + col];
        const float* b1 = b0 + UDW;
#pragma unroll
        for (int ss = 0; ss < 2; ++ss) {
            int s = h * 2 + ss;                      // this wave's m-half
            float adjv = adj_lds[c * 64 + s * 16 + col];
            u32x4 pk;
            pk[0] = pack_bf2(b0[s * 16],       b0[s * 16 + 64]);
            pk[1] = pack_bf2(b0[s * 16 + 128], b0[s * 16 + 192]);
            pk[2] = pack_bf2(b1[s * 16],       b1[s * 16 + 64]);
            pk[3] = pack_bf2(b1[s * 16 + 128], b1[s * 16 + 192]);
            bf16x8 bf = __builtin_bit_cast(bf16x8, pk);
#pragma unroll
            for (int bt = 0; bt < 4; ++bt) {
                f32x4 d = __builtin_amdgcn_mfma_f32_16x16x32_bf16(
                    a_frag[bt], bf, (f32x4){0.f, 0.f, 0.f, 0.f}, 0, 0, 0);
#pragma unroll
                for (int r = 0; r < 4; ++r)
                    g_acc[bt][r] += fmaxf(d[r], 0.0f) * adjv;
            }
        }

        // refill: chunk c+2 into buffer (c+2)%3 (readers of c, c+1 untouched)
        if (c < 14) {
            int nc = c + 2;
            async_copy16(g0 + nc * 64, &ea_lds[nc % 3][(2 * wave + 0) * UDW]);
            async_copy16(g1 + nc * 64, &ea_lds[nc % 3][(2 * wave + 1) * UDW]);
        }
    }

    // reduce over the 16 m-lanes (col); col==0 writes this wave's 64 partials
#pragma unroll
    for (int bt = 0; bt < 4; ++bt)
#pragma unroll
        for (int r = 0; r < 4; ++r) {
            float v = g_acc[bt][r];
            v += __shfl_xor(v, 1);
            v += __shfl_xor(v, 2);
            v += __shfl_xor(v, 4);
            v += __shfl_xor(v, 8);
            if (col == 0) gred[wave][bt * 16 + quad * 4 + r] = v;
        }
    __syncthreads();
    if (tid < OUT_CH)
        gs[tid] = (tid < 64) ? (gred[0][tid] + gred[1][tid])
                             : (gred[2][tid - 64] + gred[3][tid - 64]);
    __syncthreads();

    // epilogue: e_compress(G@L2) + adj@PF, split across thread-halves
    int o = tid & 127;
    int hf = tid >> 7;
    float acc = 0.f;
    int blo = hf * 64, bhi = hf ? (OUT_CH - 1) : 64;
#pragma unroll 8
    for (int b = blo; b < bhi; ++b)
        acc += gs[b] * L2[b * OUT_CH + o];

    float a0 = 0.f, a1 = 0.f, a2 = 0.f, a3 = 0.f;
    const float* pf = PF + (size_t)(hf * 512) * OUT_CH + o;
    const float* aw = &adj_lds[hf * 512];
    for (int mm = 0; mm < 512; mm += 4) {
        a0 += aw[mm + 0] * pf[(size_t)(mm + 0) * OUT_CH];
        a1 += aw[mm + 1] * pf[(size_t)(mm + 1) * OUT_CH];
        a2 += aw[mm + 2] * pf[(size_t)(mm + 2) * OUT_CH];
        a3 += aw[mm + 3] * pf[(size_t)(mm + 3) * OUT_CH];
    }
    acc += (a0 + a1) + (a2 + a3);
    part[hf][o] = acc;
    __syncthreads();
    if (tid < 128)
        out[(size_t)n * OUT_CH + tid] =
            part[0][tid] + part[1][tid] + R[(size_t)n * OUT_CH + tid] + bias[tid];
}

extern "C" void kernel_launch(void* const* d_in, const int* in_sizes, int n_in,
                              void* d_out, int out_size, void* d_ws, size_t ws_size,
                              hipStream_t stream) {
    const float* node_mat    = (const float*)d_in[0];
    const float* adj         = (const float*)d_in[1];
    const float* edge_adj    = (const float*)d_in[2];
    const float* node_weight = (const float*)d_in[3];
    const float* edge_lay_1  = (const float*)d_in[4];
    const float* edge_lay_2  = (const float*)d_in[5];
    const float* root        = (const float*)d_in[6];
    const float* bias        = (const float*)d_in[7];
    float* out = (float*)d_out;

    float* PF = (float*)d_ws;                 // 512 KB
    float* R  = PF + NN * OUT_CH;             // 512 KB

    node_gemm_kernel<<<64, 256, 0, stream>>>(node_mat, node_weight, root, PF, R);
    fused_kernel<<<NN, 256, 0, stream>>>(edge_adj, adj, edge_lay_1, edge_lay_2,
                                         PF, R, bias, out);
}